// Round 1
// baseline (4938.478 us; speedup 1.0000x reference)
//
#include <hip/hip_runtime.h>

#define H 64
#define T_STEPS 2048
#define NGATES 256   // 4*H

__device__ __forceinline__ float sigmoid_f(float x) {
    return 1.0f / (1.0f + __expf(-x));
}
__device__ __forceinline__ float tanh_f(float x) {
    // tanh(x) = 2*sigmoid(2x) - 1 ; saturates correctly at +/-1 via inf/0
    return 2.0f / (1.0f + __expf(-2.0f * x)) - 1.0f;
}

// 64-long dot product: w in registers (unrolled const-indexed), hsrc in LDS
// (wave-uniform addresses -> broadcast ds_read_b128, conflict-free).
__device__ __forceinline__ float dot64(const float* w, const float* hsrc) {
    float a0 = 0.f, a1 = 0.f, a2 = 0.f, a3 = 0.f;
#pragma unroll
    for (int j = 0; j < H; j += 4) {
        float4 hv = *(const float4*)(hsrc + j);
        a0 += w[j]     * hv.x;
        a1 += w[j + 1] * hv.y;
        a2 += w[j + 2] * hv.z;
        a3 += w[j + 3] * hv.w;
    }
    return (a0 + a1) + (a2 + a3);
}

__device__ __forceinline__ void load64(float* w, const float* __restrict__ src) {
    const float4* p = (const float4*)src;
#pragma unroll
    for (int i = 0; i < 16; ++i) {
        float4 v = p[i];
        w[4 * i] = v.x; w[4 * i + 1] = v.y; w[4 * i + 2] = v.z; w[4 * i + 3] = v.w;
    }
}

__device__ __forceinline__ void gate_update(int tid, int gsel, float preact,
                                            float* gates, float* hout, float& c) {
    float act = (gsel == 2) ? tanh_f(preact) : sigmoid_f(preact);
    gates[tid] = act;
    __syncthreads();
    if (tid < H) {
        float ig = gates[tid];
        float fg = gates[H + tid];
        float gg = gates[2 * H + tid];
        float og = gates[3 * H + tid];
        c = fg * c + ig * gg;
        hout[tid] = og * tanh_f(c);
    }
    __syncthreads();
}

__global__ __launch_bounds__(256, 1)
void lstm3_fused(const float* __restrict__ x,
                 const float* __restrict__ Wih0, const float* __restrict__ Whh0,
                 const float* __restrict__ bih0, const float* __restrict__ bhh0,
                 const float* __restrict__ Wih1, const float* __restrict__ Whh1,
                 const float* __restrict__ bih1, const float* __restrict__ bhh1,
                 const float* __restrict__ Wih2, const float* __restrict__ Whh2,
                 const float* __restrict__ bih2, const float* __restrict__ bhh2,
                 const float* __restrict__ Wout, const float* __restrict__ bout,
                 float* __restrict__ out)
{
    __shared__ __align__(16) float xs[T_STEPS * 2];   // 16 KB: this batch's input sequence
    __shared__ __align__(16) float h0[H], h1[H], h2[H];
    __shared__ __align__(16) float gates[NGATES];

    const int tid = threadIdx.x;
    const int b   = blockIdx.x;
    const int gsel = tid >> 6;   // 0:i 1:f 2:g(tanh) 3:o  (wave-uniform)

    // ---- stage x[b, :, :] (4096 floats) into LDS, coalesced float4 ----
    {
        const float4* xsrc = (const float4*)(x + (size_t)b * T_STEPS * 2);
        float4* xdst = (float4*)xs;
#pragma unroll
        for (int i = 0; i < 4; ++i)
            xdst[tid + 256 * i] = xsrc[tid + 256 * i];
    }

    // ---- weights for this thread's gate row -> registers (~325 VGPRs) ----
    float w0h[H], w1x[H], w1h[H], w2x[H], w2h[H];
    float w0x0 = Wih0[tid * 2 + 0];
    float w0x1 = Wih0[tid * 2 + 1];
    load64(w0h, Whh0 + tid * H);
    load64(w1x, Wih1 + tid * H);
    load64(w1h, Whh1 + tid * H);
    load64(w2x, Wih2 + tid * H);
    load64(w2h, Whh2 + tid * H);
    const float bias0 = bih0[tid] + bhh0[tid];
    const float bias1 = bih1[tid] + bhh1[tid];
    const float bias2 = bih2[tid] + bhh2[tid];

    if (tid < H) { h0[tid] = 0.f; h1[tid] = 0.f; h2[tid] = 0.f; }
    float c0 = 0.f, c1 = 0.f, c2 = 0.f;
    __syncthreads();

#pragma unroll 1
    for (int t = 0; t < T_STEPS; ++t) {
        // ---- layer 0: input = x_t (2 floats), recurrent = h0 ----
        float2 xt = *(const float2*)&xs[2 * t];
        float p0 = bias0 + w0x0 * xt.x + w0x1 * xt.y + dot64(w0h, h0);
        gate_update(tid, gsel, p0, gates, h0, c0);

        // ---- layer 1: input = h0 (fresh), recurrent = h1 ----
        float p1 = bias1 + dot64(w1x, h0) + dot64(w1h, h1);
        gate_update(tid, gsel, p1, gates, h1, c1);

        // ---- layer 2: input = h1 (fresh), recurrent = h2 ----
        float p2 = bias2 + dot64(w2x, h1) + dot64(w2h, h2);
        gate_update(tid, gsel, p2, gates, h2, c2);
    }

    // ---- fused projection: out[b, :] = h2_last @ Wout^T + bout ----
    if (tid < 11) {
        float acc = bout[tid];
#pragma unroll
        for (int j = 0; j < H; ++j)
            acc += Wout[tid * H + j] * h2[j];
        out[b * 11 + tid] = acc;
    }
}

extern "C" void kernel_launch(void* const* d_in, const int* in_sizes, int n_in,
                              void* d_out, int out_size, void* d_ws, size_t ws_size,
                              hipStream_t stream) {
    const float* x    = (const float*)d_in[0];
    const float* Wih0 = (const float*)d_in[1];
    const float* Whh0 = (const float*)d_in[2];
    const float* bih0 = (const float*)d_in[3];
    const float* bhh0 = (const float*)d_in[4];
    const float* Wih1 = (const float*)d_in[5];
    const float* Whh1 = (const float*)d_in[6];
    const float* bih1 = (const float*)d_in[7];
    const float* bhh1 = (const float*)d_in[8];
    const float* Wih2 = (const float*)d_in[9];
    const float* Whh2 = (const float*)d_in[10];
    const float* bih2 = (const float*)d_in[11];
    const float* bhh2 = (const float*)d_in[12];
    const float* Wout = (const float*)d_in[13];
    const float* bout = (const float*)d_in[14];
    float* out = (float*)d_out;

    lstm3_fused<<<256, 256, 0, stream>>>(x,
        Wih0, Whh0, bih0, bhh0,
        Wih1, Whh1, bih1, bhh1,
        Wih2, Whh2, bih2, bhh2,
        Wout, bout, out);
}

// Round 6
// 3972.837 us; speedup vs baseline: 1.2431x; 1.2431x over previous
//
#include <hip/hip_runtime.h>

#define H 64
#define T_STEPS 2048

__device__ __forceinline__ float sigmoid_f(float x) {
    return 1.0f / (1.0f + __expf(-x));
}
__device__ __forceinline__ float tanh_f(float x) {
    // tanh(x) = 2*sigmoid(2x) - 1 ; saturates correctly via inf/0
    return 2.0f / (1.0f + __expf(-2.0f * x)) - 1.0f;
}

// dot of two float4s -- FUNCTION, not macro (macro param 'w' collided with
// the .w member token in round 4: preprocessor replaces identifiers even
// after '.').
__device__ __forceinline__ float d4(float4 a, float4 b) {
    return a.x * b.x + a.y * b.y + a.z * b.z + a.w * b.w;
}

// ---- weight half-rows as NAMED float4 registers (SROA-proof) ----
#define DECL8(W)  float4 W##0, W##1, W##2, W##3, W##4, W##5, W##6, W##7
#define LOAD8(W, src) do { const float4* _p = (const float4*)(src); \
    W##0=_p[0]; W##1=_p[1]; W##2=_p[2]; W##3=_p[3];                 \
    W##4=_p[4]; W##5=_p[5]; W##6=_p[6]; W##7=_p[7]; } while (0)
// hp: const float4* into LDS (2 distinct addrs/wave -> broadcast ds_read_b128)
#define DOT32(W, hp) (((d4(W##0,(hp)[0]) + d4(W##1,(hp)[1]))   \
                     + (d4(W##2,(hp)[2]) + d4(W##3,(hp)[3])))  \
                     + ((d4(W##4,(hp)[4]) + d4(W##5,(hp)[5]))  \
                     + (d4(W##6,(hp)[6]) + d4(W##7,(hp)[7]))))

// Block = 512 threads = 8 waves. Thread pair (2g, 2g+1) owns gate row g:
// each lane holds HALF of every weight row (40 float4 = 160 VGPRs of weights).
// Halves combined with __shfl_xor(.,1) (partners adjacent, same wave).
__global__ __launch_bounds__(512, 2)
void lstm3_fused(const float* __restrict__ x,
                 const float* __restrict__ Wih0, const float* __restrict__ Whh0,
                 const float* __restrict__ bih0, const float* __restrict__ bhh0,
                 const float* __restrict__ Wih1, const float* __restrict__ Whh1,
                 const float* __restrict__ bih1, const float* __restrict__ bhh1,
                 const float* __restrict__ Wih2, const float* __restrict__ Whh2,
                 const float* __restrict__ bih2, const float* __restrict__ bhh2,
                 const float* __restrict__ Wout, const float* __restrict__ bout,
                 float* __restrict__ out)
{
    __shared__ __align__(16) float xs[T_STEPS * 2];   // 16 KB input sequence
    __shared__ __align__(16) float h0[H], h1[H], h2[H];
    __shared__ __align__(16) float gates[4 * H];

    const int tid  = threadIdx.x;
    const int b    = blockIdx.x;
    const int g    = tid >> 1;      // gate row 0..255
    const int half = tid & 1;       // 0: k in [0,32), 1: k in [32,64)
    const int hoff = half * 32;
    const int gtype = tid >> 7;     // 0:i 1:f 2:g(tanh) 3:o  (wave-uniform)
    const int j    = tid >> 1;      // cell index when tid < 128

    // ---- stage x[b,:,:] (4096 floats) into LDS, coalesced float4 ----
    {
        const float4* xsrc = (const float4*)(x + (size_t)b * T_STEPS * 2);
        float4* xdst = (float4*)xs;
        xdst[tid]       = xsrc[tid];
        xdst[tid + 512] = xsrc[tid + 512];
    }

    // ---- this thread's half-rows -> named registers ----
    DECL8(A);  // Whh0 half-row
    DECL8(B);  // Wih1 half-row
    DECL8(C);  // Whh1 half-row
    DECL8(D);  // Wih2 half-row
    DECL8(E);  // Whh2 half-row
    LOAD8(A, Whh0 + g * H + hoff);
    LOAD8(B, Wih1 + g * H + hoff);
    LOAD8(C, Whh1 + g * H + hoff);
    LOAD8(D, Wih2 + g * H + hoff);
    LOAD8(E, Whh2 + g * H + hoff);
    const float w0x0 = Wih0[g * 2 + 0];
    const float w0x1 = Wih0[g * 2 + 1];
    const float bias0 = bih0[g] + bhh0[g];
    const float bias1 = bih1[g] + bhh1[g];
    const float bias2 = bih2[g] + bhh2[g];

    if (tid < H) { h0[tid] = 0.f; h1[tid] = 0.f; h2[tid] = 0.f; }
    float c0 = 0.f, c1 = 0.f, c2 = 0.f;   // live in tid<128 (both pair lanes)
    __syncthreads();

#pragma unroll 1
    for (int t = 0; t < T_STEPS; ++t) {
        const float4* h0p = (const float4*)(h0 + hoff);
        const float4* h1p = (const float4*)(h1 + hoff);
        const float4* h2p = (const float4*)(h2 + hoff);

        // ================= layer 0 =================
        float ph = DOT32(A, h0p);
        if (!half) {
            float2 xt = *(const float2*)&xs[2 * t];
            ph += w0x0 * xt.x + w0x1 * xt.y;   // x-term counted once (even lane)
        }
        float p   = bias0 + ph + __shfl_xor(ph, 1);
        float act = (gtype == 2) ? tanh_f(p) : sigmoid_f(p);
        if (!half) gates[g] = act;
        __syncthreads();
        if (tid < 128) {
            float ig = gates[j], fg = gates[H + j];
            float gg = gates[2 * H + j], og = gates[3 * H + j];
            c0 = fg * c0 + ig * gg;
            if (!half) h0[j] = og * tanh_f(c0);
        }
        __syncthreads();

        // ================= layer 1 =================
        ph  = DOT32(B, h0p) + DOT32(C, h1p);
        p   = bias1 + ph + __shfl_xor(ph, 1);
        act = (gtype == 2) ? tanh_f(p) : sigmoid_f(p);
        if (!half) gates[g] = act;
        __syncthreads();
        if (tid < 128) {
            float ig = gates[j], fg = gates[H + j];
            float gg = gates[2 * H + j], og = gates[3 * H + j];
            c1 = fg * c1 + ig * gg;
            if (!half) h1[j] = og * tanh_f(c1);
        }
        __syncthreads();

        // ================= layer 2 =================
        ph  = DOT32(D, h1p) + DOT32(E, h2p);
        p   = bias2 + ph + __shfl_xor(ph, 1);
        act = (gtype == 2) ? tanh_f(p) : sigmoid_f(p);
        if (!half) gates[g] = act;
        __syncthreads();
        if (tid < 128) {
            float ig = gates[j], fg = gates[H + j];
            float gg = gates[2 * H + j], og = gates[3 * H + j];
            c2 = fg * c2 + ig * gg;
            if (!half) h2[j] = og * tanh_f(c2);
        }
        __syncthreads();
    }

    // ---- fused projection: out[b,:] = h2_last @ Wout^T + bout ----
    if (tid < 11) {
        float acc = bout[tid];
#pragma unroll
        for (int jj = 0; jj < H; ++jj)
            acc += Wout[tid * H + jj] * h2[jj];
        out[b * 11 + tid] = acc;
    }
}

extern "C" void kernel_launch(void* const* d_in, const int* in_sizes, int n_in,
                              void* d_out, int out_size, void* d_ws, size_t ws_size,
                              hipStream_t stream) {
    const float* x    = (const float*)d_in[0];
    const float* Wih0 = (const float*)d_in[1];
    const float* Whh0 = (const float*)d_in[2];
    const float* bih0 = (const float*)d_in[3];
    const float* bhh0 = (const float*)d_in[4];
    const float* Wih1 = (const float*)d_in[5];
    const float* Whh1 = (const float*)d_in[6];
    const float* bih1 = (const float*)d_in[7];
    const float* bhh1 = (const float*)d_in[8];
    const float* Wih2 = (const float*)d_in[9];
    const float* Whh2 = (const float*)d_in[10];
    const float* bih2 = (const float*)d_in[11];
    const float* bhh2 = (const float*)d_in[12];
    const float* Wout = (const float*)d_in[13];
    const float* bout = (const float*)d_in[14];
    float* out = (float*)d_out;

    lstm3_fused<<<256, 512, 0, stream>>>(x,
        Wih0, Whh0, bih0, bhh0,
        Wih1, Whh1, bih1, bhh1,
        Wih2, Whh2, bih2, bhh2,
        Wout, bout, out);
}

// Round 8
// 3773.699 us; speedup vs baseline: 1.3087x; 1.0528x over previous
//
#include <hip/hip_runtime.h>

#define H 64
#define T_STEPS 2048

__device__ __forceinline__ float sigmoid_f(float x) {
    return 1.0f / (1.0f + __expf(-x));
}
__device__ __forceinline__ float tanh_f(float x) {
    // tanh(x) = 2*sigmoid(2x) - 1 ; saturates correctly via inf/0
    return 2.0f / (1.0f + __expf(-2.0f * x)) - 1.0f;
}

// dot of two float4s -- FUNCTION, not macro (a macro param named 'w' would
// collide with the .w member token under the preprocessor).
__device__ __forceinline__ float d4(float4 a, float4 b) {
    return a.x * b.x + a.y * b.y + a.z * b.z + a.w * b.w;
}

// ---- weight quarter-rows as NAMED float4 registers (SROA-proof) ----
#define DECL4(W)  float4 W##0, W##1, W##2, W##3
#define LOAD4(W, src) do { const float4* _p = (const float4*)(src); \
    W##0=_p[0]; W##1=_p[1]; W##2=_p[2]; W##3=_p[3]; } while (0)
// hp: const float4* into LDS (4 distinct addrs/wave -> broadcast reads)
#define DOT16(W, hp) ((d4(W##0,(hp)[0]) + d4(W##1,(hp)[1]))  \
                    + (d4(W##2,(hp)[2]) + d4(W##3,(hp)[3])))

// Block = 1024 threads = 16 waves = 4 waves/SIMD (structurally forced: a
// 1024-thread block only launches if all 16 waves fit one CU -> VGPR <= 128).
// Lane quad (4g..4g+3) owns gate row g; each lane holds a QUARTER of every
// weight row: 20 float4 = 80 VGPRs of weights, ~115 total -- fits the 128
// budget the allocator picked in R1/R6 instead of fighting it.
// Quarter-dots combined with __shfl_xor 1 then 2 (quad is in-wave).
__global__ __attribute__((amdgpu_flat_work_group_size(1024, 1024),
                          amdgpu_waves_per_eu(4, 4)))
void lstm3_fused(const float* __restrict__ x,
                 const float* __restrict__ Wih0, const float* __restrict__ Whh0,
                 const float* __restrict__ bih0, const float* __restrict__ bhh0,
                 const float* __restrict__ Wih1, const float* __restrict__ Whh1,
                 const float* __restrict__ bih1, const float* __restrict__ bhh1,
                 const float* __restrict__ Wih2, const float* __restrict__ Whh2,
                 const float* __restrict__ bih2, const float* __restrict__ bhh2,
                 const float* __restrict__ Wout, const float* __restrict__ bout,
                 float* __restrict__ out)
{
    __shared__ __align__(16) float xs[T_STEPS * 2];   // 16 KB input sequence
    __shared__ __align__(16) float h0[H], h1[H], h2[H];
    __shared__ __align__(16) float gates[4 * H];

    const int tid  = threadIdx.x;
    const int b    = blockIdx.x;
    const int g    = tid >> 2;      // gate row 0..255
    const int q    = tid & 3;       // quarter 0..3: k in [16q, 16q+16)
    const int qoff = q * 16;
    const int gtype = tid >> 8;     // 0:i 1:f 2:g(tanh) 3:o  (wave-uniform)

    // ---- stage x[b,:,:] (4096 floats = 1024 float4) into LDS ----
    {
        const float4* xsrc = (const float4*)(x + (size_t)b * T_STEPS * 2);
        ((float4*)xs)[tid] = xsrc[tid];
    }

    // ---- this thread's quarter-rows -> named registers (80 VGPRs) ----
    DECL4(A);  // Whh0 quarter-row
    DECL4(B);  // Wih1 quarter-row
    DECL4(C);  // Whh1 quarter-row
    DECL4(D);  // Wih2 quarter-row
    DECL4(E);  // Whh2 quarter-row
    LOAD4(A, Whh0 + g * H + qoff);
    LOAD4(B, Wih1 + g * H + qoff);
    LOAD4(C, Whh1 + g * H + qoff);
    LOAD4(D, Wih2 + g * H + qoff);
    LOAD4(E, Whh2 + g * H + qoff);
    const float w0x0 = Wih0[g * 2 + 0];
    const float w0x1 = Wih0[g * 2 + 1];
    const float bias0 = bih0[g] + bhh0[g];
    const float bias1 = bih1[g] + bhh1[g];
    const float bias2 = bih2[g] + bhh2[g];

    if (tid < H) { h0[tid] = 0.f; h1[tid] = 0.f; h2[tid] = 0.f; }
    float c0 = 0.f, c1 = 0.f, c2 = 0.f;   // meaningful in tid<64 (wave 0)
    __syncthreads();

#pragma unroll 1
    for (int t = 0; t < T_STEPS; ++t) {
        const float4* h0p = (const float4*)(h0 + qoff);
        const float4* h1p = (const float4*)(h1 + qoff);
        const float4* h2p = (const float4*)(h2 + qoff);

        // ================= layer 0 =================
        float ph = DOT16(A, h0p);
        if (q == 0) {
            float2 xt = *(const float2*)&xs[2 * t];
            ph += w0x0 * xt.x + w0x1 * xt.y;   // x-term counted once per quad
        }
        ph += __shfl_xor(ph, 1);
        ph += __shfl_xor(ph, 2);
        float p   = bias0 + ph;
        float act = (gtype == 2) ? tanh_f(p) : sigmoid_f(p);
        if (q == 0) gates[g] = act;
        __syncthreads();
        if (tid < H) {
            float ig = gates[tid], fg = gates[H + tid];
            float gg = gates[2 * H + tid], og = gates[3 * H + tid];
            c0 = fg * c0 + ig * gg;
            h0[tid] = og * tanh_f(c0);
        }
        __syncthreads();

        // ================= layer 1 =================
        ph  = DOT16(B, h0p) + DOT16(C, h1p);
        ph += __shfl_xor(ph, 1);
        ph += __shfl_xor(ph, 2);
        p   = bias1 + ph;
        act = (gtype == 2) ? tanh_f(p) : sigmoid_f(p);
        if (q == 0) gates[g] = act;
        __syncthreads();
        if (tid < H) {
            float ig = gates[tid], fg = gates[H + tid];
            float gg = gates[2 * H + tid], og = gates[3 * H + tid];
            c1 = fg * c1 + ig * gg;
            h1[tid] = og * tanh_f(c1);
        }
        __syncthreads();

        // ================= layer 2 =================
        ph  = DOT16(D, h1p) + DOT16(E, h2p);
        ph += __shfl_xor(ph, 1);
        ph += __shfl_xor(ph, 2);
        p   = bias2 + ph;
        act = (gtype == 2) ? tanh_f(p) : sigmoid_f(p);
        if (q == 0) gates[g] = act;
        __syncthreads();
        if (tid < H) {
            float ig = gates[tid], fg = gates[H + tid];
            float gg = gates[2 * H + tid], og = gates[3 * H + tid];
            c2 = fg * c2 + ig * gg;
            h2[tid] = og * tanh_f(c2);
        }
        __syncthreads();
    }

    // ---- fused projection: out[b,:] = h2_last @ Wout^T + bout ----
    if (tid < 11) {
        float acc = bout[tid];
#pragma unroll
        for (int jj = 0; jj < H; ++jj)
            acc += Wout[tid * H + jj] * h2[jj];
        out[b * 11 + tid] = acc;
    }
}

extern "C" void kernel_launch(void* const* d_in, const int* in_sizes, int n_in,
                              void* d_out, int out_size, void* d_ws, size_t ws_size,
                              hipStream_t stream) {
    const float* x    = (const float*)d_in[0];
    const float* Wih0 = (const float*)d_in[1];
    const float* Whh0 = (const float*)d_in[2];
    const float* bih0 = (const float*)d_in[3];
    const float* bhh0 = (const float*)d_in[4];
    const float* Wih1 = (const float*)d_in[5];
    const float* Whh1 = (const float*)d_in[6];
    const float* bih1 = (const float*)d_in[7];
    const float* bhh1 = (const float*)d_in[8];
    const float* Wih2 = (const float*)d_in[9];
    const float* Whh2 = (const float*)d_in[10];
    const float* bih2 = (const float*)d_in[11];
    const float* bhh2 = (const float*)d_in[12];
    const float* Wout = (const float*)d_in[13];
    const float* bout = (const float*)d_in[14];
    float* out = (float*)d_out;

    lstm3_fused<<<256, 1024, 0, stream>>>(x,
        Wih0, Whh0, bih0, bhh0,
        Wih1, Whh1, bih1, bhh1,
        Wih2, Whh2, bih2, bhh2,
        Wout, bout, out);
}

// Round 9
// 3600.880 us; speedup vs baseline: 1.3715x; 1.0480x over previous
//
#include <hip/hip_runtime.h>

#define H 64
#define T_STEPS 2048

typedef _Float16 h2_t __attribute__((ext_vector_type(2)));
typedef _Float16 h8_t __attribute__((ext_vector_type(8)));

__device__ __forceinline__ float sigmoid_f(float x) {
    return 1.0f / (1.0f + __expf(-x));
}
__device__ __forceinline__ float tanh_f(float x) {
    return 2.0f / (1.0f + __expf(-2.0f * x)) - 1.0f;
}

// v_dot2_f32_f16: 2-way f16 dot, fp32 accumulate (exact products).
#if __has_builtin(__builtin_amdgcn_fdot2)
__device__ __forceinline__ float dot2(h2_t a, h2_t b, float c) {
    return __builtin_amdgcn_fdot2(a, b, c, false);
}
#else
__device__ __forceinline__ float dot2(h2_t a, h2_t b, float c) {
    float r;
    asm volatile("v_dot2_f32_f16 %0, %1, %2, %3"
                 : "=v"(r) : "v"(a), "v"(b), "v"(c));
    return r;
}
#endif

// aligned even-index h2 extraction from an h8 = pure register aliasing
#define SUB2(v, i) __builtin_shufflevector((v), (v), (i), (i) + 1)

__device__ __forceinline__ float d8(h8_t w, h8_t h, float acc) {
    acc = dot2(SUB2(w, 0), SUB2(h, 0), acc);
    acc = dot2(SUB2(w, 2), SUB2(h, 2), acc);
    acc = dot2(SUB2(w, 4), SUB2(h, 4), acc);
    acc = dot2(SUB2(w, 6), SUB2(h, 6), acc);
    return acc;
}

// load 16 fp32 weights -> two h8_t (RTN via C cast; load-time only)
__device__ __forceinline__ void cvt16(const float* __restrict__ src,
                                      h8_t& a, h8_t& b) {
    const float4* p = (const float4*)src;
    float4 v0 = p[0], v1 = p[1], v2 = p[2], v3 = p[3];
    a[0] = (_Float16)v0.x; a[1] = (_Float16)v0.y;
    a[2] = (_Float16)v0.z; a[3] = (_Float16)v0.w;
    a[4] = (_Float16)v1.x; a[5] = (_Float16)v1.y;
    a[6] = (_Float16)v1.z; a[7] = (_Float16)v1.w;
    b[0] = (_Float16)v2.x; b[1] = (_Float16)v2.y;
    b[2] = (_Float16)v2.z; b[3] = (_Float16)v2.w;
    b[4] = (_Float16)v3.x; b[5] = (_Float16)v3.y;
    b[6] = (_Float16)v3.z; b[7] = (_Float16)v3.w;
}

// Block = 1024 threads = 16 waves. Lane quad (4g..4g+3) owns gate row g;
// each lane holds a QUARTER of every weight row as f16 pairs:
// 5 matrices x 2 h8_t = 10 h8_t = 40 VGPRs of weights. Total demand ~65
// VGPR -- aligned with the compiler's revealed 64-VGPR allocation target
// (R1/R6/R8 all sank fp32 weights to L2 reloads; at f16 any residual
// sink is L1-resident and cheap).
// h lives in LDS as packed f16 (h2_t), written by 32 cell-update lanes
// (2 cells/lane -> one ds_write_b32 each, no pack race). Dots use
// v_dot2_f32_f16 (fp32 accumulate).
__global__ __launch_bounds__(1024)
void lstm3_fused(const float* __restrict__ x,
                 const float* __restrict__ Wih0, const float* __restrict__ Whh0,
                 const float* __restrict__ bih0, const float* __restrict__ bhh0,
                 const float* __restrict__ Wih1, const float* __restrict__ Whh1,
                 const float* __restrict__ bih1, const float* __restrict__ bhh1,
                 const float* __restrict__ Wih2, const float* __restrict__ Whh2,
                 const float* __restrict__ bih2, const float* __restrict__ bhh2,
                 const float* __restrict__ Wout, const float* __restrict__ bout,
                 float* __restrict__ out)
{
    __shared__ __align__(16) float xs[T_STEPS * 2];   // 16 KB input sequence
    __shared__ __align__(16) h2_t h16_0[H / 2];       // h as packed f16
    __shared__ __align__(16) h2_t h16_1[H / 2];
    __shared__ __align__(16) h2_t h16_2[H / 2];
    __shared__ __align__(16) float h2f[H];            // fp32 h2 copy (projection)
    __shared__ __align__(16) float gates[4 * H];

    const int tid   = threadIdx.x;
    const int b     = blockIdx.x;
    const int g     = tid >> 2;     // gate row 0..255
    const int q     = tid & 3;      // quarter: k in [16q, 16q+16)
    const int gtype = tid >> 8;     // 0:i 1:f 2:g(tanh) 3:o (wave-uniform)

    // ---- stage x[b,:,:] (4096 floats = 1024 float4) into LDS ----
    ((float4*)xs)[tid] = ((const float4*)(x + (size_t)b * T_STEPS * 2))[tid];

    // ---- this lane's f16 quarter-rows (10 named h8_t = 40 VGPRs) ----
    h8_t A0, A1, B0, B1, C0, C1, D0, D1, E0, E1;
    cvt16(Whh0 + g * H + q * 16, A0, A1);
    cvt16(Wih1 + g * H + q * 16, B0, B1);
    cvt16(Whh1 + g * H + q * 16, C0, C1);
    cvt16(Wih2 + g * H + q * 16, D0, D1);
    cvt16(Whh2 + g * H + q * 16, E0, E1);
    const float w0x0  = Wih0[g * 2 + 0];   // layer-0 x-part stays fp32 exact
    const float w0x1  = Wih0[g * 2 + 1];
    const float bias0 = bih0[g] + bhh0[g];
    const float bias1 = bih1[g] + bhh1[g];
    const float bias2 = bih2[g] + bhh2[g];

    if (tid < 32) {
        h2_t hz; hz[0] = (_Float16)0.f; hz[1] = (_Float16)0.f;
        h16_0[tid] = hz; h16_1[tid] = hz; h16_2[tid] = hz;
        ((float2*)h2f)[tid] = make_float2(0.f, 0.f);
    }
    // cell state: lane tid<32 owns cells 2*tid, 2*tid+1 (fp32, registers)
    float c0a = 0.f, c0b = 0.f, c1a = 0.f, c1b = 0.f, c2a = 0.f, c2b = 0.f;
    __syncthreads();

    const h8_t* h0p = (const h8_t*)h16_0;  // 8 h8_t per layer
    const h8_t* h1p = (const h8_t*)h16_1;
    const h8_t* h2p = (const h8_t*)h16_2;

#pragma unroll 1
    for (int t = 0; t < T_STEPS; ++t) {
        // ================= layer 0 =================
        float ph = d8(A1, h0p[2 * q + 1], d8(A0, h0p[2 * q], 0.f));
        if (q == 0) {
            float2 xt = *(const float2*)&xs[2 * t];
            ph += w0x0 * xt.x + w0x1 * xt.y;   // once per quad
        }
        ph += __shfl_xor(ph, 1);
        ph += __shfl_xor(ph, 2);
        float p   = bias0 + ph;
        float act = (gtype == 2) ? tanh_f(p) : sigmoid_f(p);
        if (q == 0) gates[g] = act;
        __syncthreads();
        if (tid < 32) {
            const int a = 2 * tid, bb = a + 1;
            float iga = gates[a],       igb = gates[bb];
            float fga = gates[64 + a],  fgb = gates[64 + bb];
            float gga = gates[128 + a], ggb = gates[128 + bb];
            float oga = gates[192 + a], ogb = gates[192 + bb];
            c0a = fga * c0a + iga * gga;
            c0b = fgb * c0b + igb * ggb;
            float ha = oga * tanh_f(c0a), hb = ogb * tanh_f(c0b);
            h2_t hp; hp[0] = (_Float16)ha; hp[1] = (_Float16)hb;
            h16_0[tid] = hp;
        }
        __syncthreads();

        // ================= layer 1 =================
        ph = d8(B1, h0p[2 * q + 1], d8(B0, h0p[2 * q], 0.f))
           + d8(C1, h1p[2 * q + 1], d8(C0, h1p[2 * q], 0.f));
        ph += __shfl_xor(ph, 1);
        ph += __shfl_xor(ph, 2);
        p   = bias1 + ph;
        act = (gtype == 2) ? tanh_f(p) : sigmoid_f(p);
        if (q == 0) gates[g] = act;
        __syncthreads();
        if (tid < 32) {
            const int a = 2 * tid, bb = a + 1;
            float iga = gates[a],       igb = gates[bb];
            float fga = gates[64 + a],  fgb = gates[64 + bb];
            float gga = gates[128 + a], ggb = gates[128 + bb];
            float oga = gates[192 + a], ogb = gates[192 + bb];
            c1a = fga * c1a + iga * gga;
            c1b = fgb * c1b + igb * ggb;
            float ha = oga * tanh_f(c1a), hb = ogb * tanh_f(c1b);
            h2_t hp; hp[0] = (_Float16)ha; hp[1] = (_Float16)hb;
            h16_1[tid] = hp;
        }
        __syncthreads();

        // ================= layer 2 =================
        ph = d8(D1, h1p[2 * q + 1], d8(D0, h1p[2 * q], 0.f))
           + d8(E1, h2p[2 * q + 1], d8(E0, h2p[2 * q], 0.f));
        ph += __shfl_xor(ph, 1);
        ph += __shfl_xor(ph, 2);
        p   = bias2 + ph;
        act = (gtype == 2) ? tanh_f(p) : sigmoid_f(p);
        if (q == 0) gates[g] = act;
        __syncthreads();
        if (tid < 32) {
            const int a = 2 * tid, bb = a + 1;
            float iga = gates[a],       igb = gates[bb];
            float fga = gates[64 + a],  fgb = gates[64 + bb];
            float gga = gates[128 + a], ggb = gates[128 + bb];
            float oga = gates[192 + a], ogb = gates[192 + bb];
            c2a = fga * c2a + iga * gga;
            c2b = fgb * c2b + igb * ggb;
            float ha = oga * tanh_f(c2a), hb = ogb * tanh_f(c2b);
            h2_t hp; hp[0] = (_Float16)ha; hp[1] = (_Float16)hb;
            h16_2[tid] = hp;
            ((float2*)h2f)[tid] = make_float2(ha, hb);  // fp32 copy for projection
        }
        __syncthreads();
    }

    // ---- fused projection: out[b,:] = h2_last @ Wout^T + bout ----
    if (tid < 11) {
        float acc = bout[tid];
#pragma unroll
        for (int jj = 0; jj < H; ++jj)
            acc += Wout[tid * H + jj] * h2f[jj];
        out[b * 11 + tid] = acc;
    }
}

extern "C" void kernel_launch(void* const* d_in, const int* in_sizes, int n_in,
                              void* d_out, int out_size, void* d_ws, size_t ws_size,
                              hipStream_t stream) {
    const float* x    = (const float*)d_in[0];
    const float* Wih0 = (const float*)d_in[1];
    const float* Whh0 = (const float*)d_in[2];
    const float* bih0 = (const float*)d_in[3];
    const float* bhh0 = (const float*)d_in[4];
    const float* Wih1 = (const float*)d_in[5];
    const float* Whh1 = (const float*)d_in[6];
    const float* bih1 = (const float*)d_in[7];
    const float* bhh1 = (const float*)d_in[8];
    const float* Wih2 = (const float*)d_in[9];
    const float* Whh2 = (const float*)d_in[10];
    const float* bih2 = (const float*)d_in[11];
    const float* bhh2 = (const float*)d_in[12];
    const float* Wout = (const float*)d_in[13];
    const float* bout = (const float*)d_in[14];
    float* out = (float*)d_out;

    lstm3_fused<<<256, 1024, 0, stream>>>(x,
        Wih0, Whh0, bih0, bhh0,
        Wih1, Whh1, bih1, bhh1,
        Wih2, Whh2, bih2, bhh2,
        Wout, bout, out);
}

// Round 11
// 3581.833 us; speedup vs baseline: 1.3788x; 1.0053x over previous
//
#include <hip/hip_runtime.h>

#define H 64
#define T_STEPS 2048

typedef _Float16 h2_t __attribute__((ext_vector_type(2)));
typedef _Float16 h8_t __attribute__((ext_vector_type(8)));

__device__ __forceinline__ float sigmoid_f(float x) {
    return 1.0f / (1.0f + __expf(-x));
}
__device__ __forceinline__ float tanh_f(float x) {
    return 2.0f / (1.0f + __expf(-2.0f * x)) - 1.0f;
}

// v_dot2_f32_f16: 2-way f16 dot, fp32 accumulate (exact products).
#if __has_builtin(__builtin_amdgcn_fdot2)
__device__ __forceinline__ float dot2(h2_t a, h2_t b, float c) {
    return __builtin_amdgcn_fdot2(a, b, c, false);
}
#else
__device__ __forceinline__ float dot2(h2_t a, h2_t b, float c) {
    float r;
    asm volatile("v_dot2_f32_f16 %0, %1, %2, %3"
                 : "=v"(r) : "v"(a), "v"(b), "v"(c));
    return r;
}
#endif

// aligned even-index h2 extraction from an h8 = pure register aliasing
#define SUB2(v, i) __builtin_shufflevector((v), (v), (i), (i) + 1)

__device__ __forceinline__ float d8(h8_t w, h8_t h, float acc) {
    acc = dot2(SUB2(w, 0), SUB2(h, 0), acc);
    acc = dot2(SUB2(w, 2), SUB2(h, 2), acc);
    acc = dot2(SUB2(w, 4), SUB2(h, 4), acc);
    acc = dot2(SUB2(w, 6), SUB2(h, 6), acc);
    return acc;
}

// load 16 fp32 weights -> two h8_t (RTN via C cast; load-time only)
__device__ __forceinline__ void cvt16(const float* __restrict__ src,
                                      h8_t& a, h8_t& b) {
    const float4* p = (const float4*)src;
    float4 v0 = p[0], v1 = p[1], v2 = p[2], v3 = p[3];
    a[0] = (_Float16)v0.x; a[1] = (_Float16)v0.y;
    a[2] = (_Float16)v0.z; a[3] = (_Float16)v0.w;
    a[4] = (_Float16)v1.x; a[5] = (_Float16)v1.y;
    a[6] = (_Float16)v1.z; a[7] = (_Float16)v1.w;
    b[0] = (_Float16)v2.x; b[1] = (_Float16)v2.y;
    b[2] = (_Float16)v2.z; b[3] = (_Float16)v2.w;
    b[4] = (_Float16)v3.x; b[5] = (_Float16)v3.y;
    b[6] = (_Float16)v3.z; b[7] = (_Float16)v3.w;
}

// Block = 1024 threads = 16 waves. Lane quad (4g..4g+3) owns gate row g;
// each lane holds a QUARTER of every weight row as f16 pairs (10 h8_t = 40
// VGPRs) plus 5 scalar constants.
//
// KEY FIX (R11): ONE asm volatile "+v" pin on the weight registers BEFORE
// the K-loop. R1/R6/R8/R9 all showed the backend sinking the loop-invariant
// weight loads into the loop as rematerializable (VGPR_Count 180/108/64/48,
// always < the weight footprint), costing ~160 KB/step/CU of L2 reload
// traffic -- the measured bottleneck. An asm volatile cannot be sunk or
// duplicated into the loop, so every in-loop use references the asm's
// output, which is NOT rematerializable from memory; with ~100 VGPR demand
// under the 128 budget of waves_per_eu(4,4) there is no pressure to spill.
// (R10 put the pin inside the loop; that build died on infra -- pre-loop is
// semantically sufficient and cheaper to compile.)
__global__ __attribute__((amdgpu_flat_work_group_size(1024, 1024),
                          amdgpu_waves_per_eu(4, 4)))
void lstm3_fused(const float* __restrict__ x,
                 const float* __restrict__ Wih0, const float* __restrict__ Whh0,
                 const float* __restrict__ bih0, const float* __restrict__ bhh0,
                 const float* __restrict__ Wih1, const float* __restrict__ Whh1,
                 const float* __restrict__ bih1, const float* __restrict__ bhh1,
                 const float* __restrict__ Wih2, const float* __restrict__ Whh2,
                 const float* __restrict__ bih2, const float* __restrict__ bhh2,
                 const float* __restrict__ Wout, const float* __restrict__ bout,
                 float* __restrict__ out)
{
    __shared__ __align__(16) float xs[T_STEPS * 2];   // 16 KB input sequence
    __shared__ __align__(16) h2_t h16_0[H / 2];       // h as packed f16
    __shared__ __align__(16) h2_t h16_1[H / 2];
    __shared__ __align__(16) h2_t h16_2[H / 2];
    __shared__ __align__(16) float h2f[H];            // fp32 h2 copy (projection)
    __shared__ __align__(16) float gates[4 * H];

    const int tid   = threadIdx.x;
    const int b     = blockIdx.x;
    const int g     = tid >> 2;     // gate row 0..255
    const int q     = tid & 3;      // quarter: k in [16q, 16q+16)
    const int gtype = tid >> 8;     // 0:i 1:f 2:g(tanh) 3:o (wave-uniform)

    // ---- stage x[b,:,:] (4096 floats = 1024 float4) into LDS ----
    ((float4*)xs)[tid] = ((const float4*)(x + (size_t)b * T_STEPS * 2))[tid];

    // ---- this lane's f16 quarter-rows (10 named h8_t = 40 VGPRs) ----
    h8_t A0, A1, B0, B1, C0, C1, D0, D1, E0, E1;
    cvt16(Whh0 + g * H + q * 16, A0, A1);
    cvt16(Wih1 + g * H + q * 16, B0, B1);
    cvt16(Whh1 + g * H + q * 16, C0, C1);
    cvt16(Wih2 + g * H + q * 16, D0, D1);
    cvt16(Whh2 + g * H + q * 16, E0, E1);
    float w0x0  = Wih0[g * 2 + 0];   // layer-0 x-part stays fp32 exact
    float w0x1  = Wih0[g * 2 + 1];
    float bias0 = bih0[g] + bhh0[g];
    float bias1 = bih1[g] + bhh1[g];
    float bias2 = bih2[g] + bhh2[g];

    // ---- pre-loop register pin (see header comment). Small statements to
    // keep the compiler's scheduling problem trivial. ----
    asm volatile("" : "+v"(A0), "+v"(A1));
    asm volatile("" : "+v"(B0), "+v"(B1));
    asm volatile("" : "+v"(C0), "+v"(C1));
    asm volatile("" : "+v"(D0), "+v"(D1));
    asm volatile("" : "+v"(E0), "+v"(E1));
    asm volatile("" : "+v"(w0x0), "+v"(w0x1));
    asm volatile("" : "+v"(bias0), "+v"(bias1), "+v"(bias2));

    if (tid < 32) {
        h2_t hz; hz[0] = (_Float16)0.f; hz[1] = (_Float16)0.f;
        h16_0[tid] = hz; h16_1[tid] = hz; h16_2[tid] = hz;
        ((float2*)h2f)[tid] = make_float2(0.f, 0.f);
    }
    // cell state: lane tid<32 owns cells 2*tid, 2*tid+1 (fp32, registers)
    float c0a = 0.f, c0b = 0.f, c1a = 0.f, c1b = 0.f, c2a = 0.f, c2b = 0.f;
    __syncthreads();

    const h8_t* h0p = (const h8_t*)h16_0;  // 8 h8_t per layer
    const h8_t* h1p = (const h8_t*)h16_1;
    const h8_t* h2p = (const h8_t*)h16_2;

#pragma unroll 1
    for (int t = 0; t < T_STEPS; ++t) {
        // ================= layer 0 =================
        float ph = d8(A1, h0p[2 * q + 1], d8(A0, h0p[2 * q], 0.f));
        if (q == 0) {
            float2 xt = *(const float2*)&xs[2 * t];
            ph += w0x0 * xt.x + w0x1 * xt.y;   // once per quad
        }
        ph += __shfl_xor(ph, 1);
        ph += __shfl_xor(ph, 2);
        float p   = bias0 + ph;
        float act = (gtype == 2) ? tanh_f(p) : sigmoid_f(p);
        if (q == 0) gates[g] = act;
        __syncthreads();
        if (tid < 32) {
            const int a = 2 * tid, bb = a + 1;
            float iga = gates[a],       igb = gates[bb];
            float fga = gates[64 + a],  fgb = gates[64 + bb];
            float gga = gates[128 + a], ggb = gates[128 + bb];
            float oga = gates[192 + a], ogb = gates[192 + bb];
            c0a = fga * c0a + iga * gga;
            c0b = fgb * c0b + igb * ggb;
            float ha = oga * tanh_f(c0a), hb = ogb * tanh_f(c0b);
            h2_t hp; hp[0] = (_Float16)ha; hp[1] = (_Float16)hb;
            h16_0[tid] = hp;
        }
        __syncthreads();

        // ================= layer 1 =================
        ph = d8(B1, h0p[2 * q + 1], d8(B0, h0p[2 * q], 0.f))
           + d8(C1, h1p[2 * q + 1], d8(C0, h1p[2 * q], 0.f));
        ph += __shfl_xor(ph, 1);
        ph += __shfl_xor(ph, 2);
        p   = bias1 + ph;
        act = (gtype == 2) ? tanh_f(p) : sigmoid_f(p);
        if (q == 0) gates[g] = act;
        __syncthreads();
        if (tid < 32) {
            const int a = 2 * tid, bb = a + 1;
            float iga = gates[a],       igb = gates[bb];
            float fga = gates[64 + a],  fgb = gates[64 + bb];
            float gga = gates[128 + a], ggb = gates[128 + bb];
            float oga = gates[192 + a], ogb = gates[192 + bb];
            c1a = fga * c1a + iga * gga;
            c1b = fgb * c1b + igb * ggb;
            float ha = oga * tanh_f(c1a), hb = ogb * tanh_f(c1b);
            h2_t hp; hp[0] = (_Float16)ha; hp[1] = (_Float16)hb;
            h16_1[tid] = hp;
        }
        __syncthreads();

        // ================= layer 2 =================
        ph = d8(D1, h1p[2 * q + 1], d8(D0, h1p[2 * q], 0.f))
           + d8(E1, h2p[2 * q + 1], d8(E0, h2p[2 * q], 0.f));
        ph += __shfl_xor(ph, 1);
        ph += __shfl_xor(ph, 2);
        p   = bias2 + ph;
        act = (gtype == 2) ? tanh_f(p) : sigmoid_f(p);
        if (q == 0) gates[g] = act;
        __syncthreads();
        if (tid < 32) {
            const int a = 2 * tid, bb = a + 1;
            float iga = gates[a],       igb = gates[bb];
            float fga = gates[64 + a],  fgb = gates[64 + bb];
            float gga = gates[128 + a], ggb = gates[128 + bb];
            float oga = gates[192 + a], ogb = gates[192 + bb];
            c2a = fga * c2a + iga * gga;
            c2b = fgb * c2b + igb * ggb;
            float ha = oga * tanh_f(c2a), hb = ogb * tanh_f(c2b);
            h2_t hp; hp[0] = (_Float16)ha; hp[1] = (_Float16)hb;
            h16_2[tid] = hp;
            ((float2*)h2f)[tid] = make_float2(ha, hb);  // fp32 copy for projection
        }
        __syncthreads();
    }

    // ---- fused projection: out[b,:] = h2_last @ Wout^T + bout ----
    if (tid < 11) {
        float acc = bout[tid];
#pragma unroll
        for (int jj = 0; jj < H; ++jj)
            acc += Wout[tid * H + jj] * h2f[jj];
        out[b * 11 + tid] = acc;
    }
}

extern "C" void kernel_launch(void* const* d_in, const int* in_sizes, int n_in,
                              void* d_out, int out_size, void* d_ws, size_t ws_size,
                              hipStream_t stream) {
    const float* x    = (const float*)d_in[0];
    const float* Wih0 = (const float*)d_in[1];
    const float* Whh0 = (const float*)d_in[2];
    const float* bih0 = (const float*)d_in[3];
    const float* bhh0 = (const float*)d_in[4];
    const float* Wih1 = (const float*)d_in[5];
    const float* Whh1 = (const float*)d_in[6];
    const float* bih1 = (const float*)d_in[7];
    const float* bhh1 = (const float*)d_in[8];
    const float* Wih2 = (const float*)d_in[9];
    const float* Whh2 = (const float*)d_in[10];
    const float* bih2 = (const float*)d_in[11];
    const float* bhh2 = (const float*)d_in[12];
    const float* Wout = (const float*)d_in[13];
    const float* bout = (const float*)d_in[14];
    float* out = (float*)d_out;

    lstm3_fused<<<256, 1024, 0, stream>>>(x,
        Wih0, Whh0, bih0, bhh0,
        Wih1, Whh1, bih1, bhh1,
        Wih2, Whh2, bih2, bhh2,
        Wout, bout, out);
}

// Round 12
// 3032.018 us; speedup vs baseline: 1.6288x; 1.1813x over previous
//
#include <hip/hip_runtime.h>

#define H 64
#define T_STEPS 2048

typedef _Float16 h2_t __attribute__((ext_vector_type(2)));
typedef _Float16 h8_t __attribute__((ext_vector_type(8)));

__device__ __forceinline__ float sigmoid_f(float x) {
    return 1.0f / (1.0f + __expf(-x));
}
__device__ __forceinline__ float tanh_f(float x) {
    return 2.0f / (1.0f + __expf(-2.0f * x)) - 1.0f;
}

#if __has_builtin(__builtin_amdgcn_fdot2)
__device__ __forceinline__ float dot2(h2_t a, h2_t b, float c) {
    return __builtin_amdgcn_fdot2(a, b, c, false);
}
#else
__device__ __forceinline__ float dot2(h2_t a, h2_t b, float c) {
    float r;
    asm volatile("v_dot2_f32_f16 %0, %1, %2, %3"
                 : "=v"(r) : "v"(a), "v"(b), "v"(c));
    return r;
}
#endif

#define SUB2(v, i) __builtin_shufflevector((v), (v), (i), (i) + 1)

__device__ __forceinline__ float d8(h8_t w, h8_t h, float acc) {
    acc = dot2(SUB2(w, 0), SUB2(h, 0), acc);
    acc = dot2(SUB2(w, 2), SUB2(h, 2), acc);
    acc = dot2(SUB2(w, 4), SUB2(h, 4), acc);
    acc = dot2(SUB2(w, 6), SUB2(h, 6), acc);
    return acc;
}

// load 16 fp32 weights -> two h8_t (load-time only)
__device__ __forceinline__ void cvt16(const float* __restrict__ src,
                                      h8_t& a, h8_t& b) {
    const float4* p = (const float4*)src;
    float4 v0 = p[0], v1 = p[1], v2 = p[2], v3 = p[3];
    a[0] = (_Float16)v0.x; a[1] = (_Float16)v0.y;
    a[2] = (_Float16)v0.z; a[3] = (_Float16)v0.w;
    a[4] = (_Float16)v1.x; a[5] = (_Float16)v1.y;
    a[6] = (_Float16)v1.z; a[7] = (_Float16)v1.w;
    b[0] = (_Float16)v2.x; b[1] = (_Float16)v2.y;
    b[2] = (_Float16)v2.z; b[3] = (_Float16)v2.w;
    b[4] = (_Float16)v3.x; b[5] = (_Float16)v3.y;
    b[6] = (_Float16)v3.z; b[7] = (_Float16)v3.w;
}

// LAYER-PIPELINED LSTM (R12). Evidence from R8->R9->R11: dur is insensitive
// to instruction count and reload bytes -> latency/serialization-bound on
// the 3-sequential-phases-per-step structure (barrier + LDS round-trip +
// 1-wave update, ~1430 cyc each). Fix: software-pipeline the 3 layers --
// at phase p: layer0 computes t=p, layer1 t=p-1, layer2 t=p-2, all
// independent via double-buffered h (reads slot (p+1)&1, writes slot p&1).
// One barrier pair per PHASE instead of per LAYER: phases 6144 -> 2050.
// Cell updates for the 3 layers run in 3 parallel waves (tid<192).
// Lane layout & numerics per layer are identical to the R9 kernel
// (quad-split rows, f16 weights/h, v_dot2 fp32 accumulate).
__global__ __attribute__((amdgpu_flat_work_group_size(1024, 1024),
                          amdgpu_waves_per_eu(4, 4)))
void lstm3_pipe(const float* __restrict__ x,
                const float* __restrict__ Wih0, const float* __restrict__ Whh0,
                const float* __restrict__ bih0, const float* __restrict__ bhh0,
                const float* __restrict__ Wih1, const float* __restrict__ Whh1,
                const float* __restrict__ bih1, const float* __restrict__ bhh1,
                const float* __restrict__ Wih2, const float* __restrict__ Whh2,
                const float* __restrict__ bih2, const float* __restrict__ bhh2,
                const float* __restrict__ Wout, const float* __restrict__ bout,
                float* __restrict__ out)
{
    __shared__ __align__(16) float xs[T_STEPS * 2];  // 16 KB input sequence
    __shared__ __align__(16) h2_t h0b[2][40];        // h per layer, 2 slots,
    __shared__ __align__(16) h2_t h1b[2][40];        // [0..31] used + pad
    __shared__ __align__(16) h2_t h2b[2][40];
    __shared__ float gt[3][4 * H];                   // gate activations
    __shared__ float h2f[H];                         // fp32 h2 (projection)

    const int tid   = threadIdx.x;
    const int b     = blockIdx.x;
    const int r     = tid >> 2;        // gate row 0..255
    const int q     = tid & 3;         // quarter: k in [16q,16q+16)
    const int gtype = r >> 6;          // 0:i 1:f 2:g 3:o (wave-uniform)
    const bool istanh = (gtype == 2);

    // ---- stage x[b,:,:] (1024 float4) ----
    ((float4*)xs)[tid] = ((const float4*)(x + (size_t)b * T_STEPS * 2))[tid];

    // ---- f16 quarter-rows (10 h8_t = 40 VGPRs) ----
    h8_t A0, A1, B0, B1, C0, C1, D0, D1, E0, E1;
    cvt16(Whh0 + r * H + q * 16, A0, A1);
    cvt16(Wih1 + r * H + q * 16, B0, B1);
    cvt16(Whh1 + r * H + q * 16, C0, C1);
    cvt16(Wih2 + r * H + q * 16, D0, D1);
    cvt16(Whh2 + r * H + q * 16, E0, E1);
    float w0x0  = Wih0[r * 2 + 0];
    float w0x1  = Wih0[r * 2 + 1];
    float bias0 = bih0[r] + bhh0[r];
    float bias1 = bih1[r] + bhh1[r];
    float bias2 = bih2[r] + bhh2[r];

    asm volatile("" : "+v"(A0), "+v"(A1));
    asm volatile("" : "+v"(B0), "+v"(B1));
    asm volatile("" : "+v"(C0), "+v"(C1));
    asm volatile("" : "+v"(D0), "+v"(D1));
    asm volatile("" : "+v"(E0), "+v"(E1));
    asm volatile("" : "+v"(w0x0), "+v"(w0x1));
    asm volatile("" : "+v"(bias0), "+v"(bias1), "+v"(bias2));

    // ---- zero-init h buffers (both slots) + h2f ----
    if (tid < 40) {
        h2_t z; z[0] = (_Float16)0.f; z[1] = (_Float16)0.f;
        h0b[0][tid] = z; h0b[1][tid] = z;
        h1b[0][tid] = z; h1b[1][tid] = z;
        h2b[0][tid] = z; h2b[1][tid] = z;
    }
    if (tid < H) h2f[tid] = 0.f;
    float cst = 0.f;   // cell state: lane tid<192 owns (layer tid>>6, cell tid&63)
    __syncthreads();

#pragma unroll 1
    for (int p = 0; p < T_STEPS + 2; ++p) {
        const int s = (p + 1) & 1;     // read slot
        const int w = p & 1;           // write slot
        const h8_t* h0s = (const h8_t*)h0b[s];
        const h8_t* h1s = (const h8_t*)h1b[s];
        const h8_t* h2s = (const h8_t*)h2b[s];
        const bool a0 = (p < T_STEPS);                   // layer0: t = p
        const bool a1 = (p >= 1) && (p < T_STEPS + 1);   // layer1: t = p-1
        const bool a2 = (p >= 2);                        // layer2: t = p-2

        // ---- gate computation, all active layers (block-uniform guards) ----
        if (a0) {
            float ph = d8(A1, h0s[2 * q + 1], d8(A0, h0s[2 * q], 0.f));
            if (q == 0) {
                float2 xt = *(const float2*)&xs[2 * p];
                ph += w0x0 * xt.x + w0x1 * xt.y;
            }
            ph += __shfl_xor(ph, 1);
            ph += __shfl_xor(ph, 2);
            float pa  = bias0 + ph;
            float act = istanh ? tanh_f(pa) : sigmoid_f(pa);
            if (q == 0) gt[0][r] = act;
        }
        if (a1) {
            float ph = d8(B1, h0s[2 * q + 1], d8(B0, h0s[2 * q], 0.f))
                     + d8(C1, h1s[2 * q + 1], d8(C0, h1s[2 * q], 0.f));
            ph += __shfl_xor(ph, 1);
            ph += __shfl_xor(ph, 2);
            float pa  = bias1 + ph;
            float act = istanh ? tanh_f(pa) : sigmoid_f(pa);
            if (q == 0) gt[1][r] = act;
        }
        if (a2) {
            float ph = d8(D1, h1s[2 * q + 1], d8(D0, h1s[2 * q], 0.f))
                     + d8(E1, h2s[2 * q + 1], d8(E0, h2s[2 * q], 0.f));
            ph += __shfl_xor(ph, 1);
            ph += __shfl_xor(ph, 2);
            float pa  = bias2 + ph;
            float act = istanh ? tanh_f(pa) : sigmoid_f(pa);
            if (q == 0) gt[2][r] = act;
        }
        __syncthreads();

        // ---- cell update: wave 0/1/2 = layer 0/1/2, in parallel ----
        if (tid < 192) {
            const int lay  = tid >> 6;    // wave-uniform
            const int cell = tid & 63;
            const bool on  = (lay == 0) ? a0 : ((lay == 1) ? a1 : a2);
            if (on) {
                float ig = gt[lay][cell];
                float fg = gt[lay][64 + cell];
                float gg = gt[lay][128 + cell];
                float og = gt[lay][192 + cell];
                cst = fg * cst + ig * gg;
                float hh = og * tanh_f(cst);
                _Float16 hx = (_Float16)hh;
                if (lay == 0)      ((_Float16*)h0b[w])[cell] = hx;
                else if (lay == 1) ((_Float16*)h1b[w])[cell] = hx;
                else             { ((_Float16*)h2b[w])[cell] = hx; h2f[cell] = hh; }
            }
        }
        __syncthreads();
    }

    // ---- fused projection: out[b,:] = h2_last @ Wout^T + bout ----
    if (tid < 11) {
        float acc = bout[tid];
#pragma unroll
        for (int jj = 0; jj < H; ++jj)
            acc += Wout[tid * H + jj] * h2f[jj];
        out[b * 11 + tid] = acc;
    }
}

extern "C" void kernel_launch(void* const* d_in, const int* in_sizes, int n_in,
                              void* d_out, int out_size, void* d_ws, size_t ws_size,
                              hipStream_t stream) {
    const float* x    = (const float*)d_in[0];
    const float* Wih0 = (const float*)d_in[1];
    const float* Whh0 = (const float*)d_in[2];
    const float* bih0 = (const float*)d_in[3];
    const float* bhh0 = (const float*)d_in[4];
    const float* Wih1 = (const float*)d_in[5];
    const float* Whh1 = (const float*)d_in[6];
    const float* bih1 = (const float*)d_in[7];
    const float* bhh1 = (const float*)d_in[8];
    const float* Wih2 = (const float*)d_in[9];
    const float* Whh2 = (const float*)d_in[10];
    const float* bih2 = (const float*)d_in[11];
    const float* bhh2 = (const float*)d_in[12];
    const float* Wout = (const float*)d_in[13];
    const float* bout = (const float*)d_in[14];
    float* out = (float*)d_out;

    lstm3_pipe<<<256, 1024, 0, stream>>>(x,
        Wih0, Whh0, bih0, bhh0,
        Wih1, Whh1, bih1, bhh1,
        Wih2, Whh2, bih2, bhh2,
        Wout, bout, out);
}

// Round 13
// 2400.158 us; speedup vs baseline: 2.0576x; 1.2633x over previous
//
#include <hip/hip_runtime.h>

#define H 64
#define T_STEPS 2048

typedef _Float16 h2_t __attribute__((ext_vector_type(2)));
typedef _Float16 h8_t __attribute__((ext_vector_type(8)));

__device__ __forceinline__ float tanh_f(float x) {
    return 2.0f / (1.0f + __expf(-2.0f * x)) - 1.0f;
}

#if __has_builtin(__builtin_amdgcn_fdot2)
__device__ __forceinline__ float dot2(h2_t a, h2_t b, float c) {
    return __builtin_amdgcn_fdot2(a, b, c, false);
}
#else
__device__ __forceinline__ float dot2(h2_t a, h2_t b, float c) {
    float r;
    asm volatile("v_dot2_f32_f16 %0, %1, %2, %3"
                 : "=v"(r) : "v"(a), "v"(b), "v"(c));
    return r;
}
#endif

#define SUB2(v, i) __builtin_shufflevector((v), (v), (i), (i) + 1)

__device__ __forceinline__ float d8(h8_t wv, h8_t hv, float acc) {
    acc = dot2(SUB2(wv, 0), SUB2(hv, 0), acc);
    acc = dot2(SUB2(wv, 2), SUB2(hv, 2), acc);
    acc = dot2(SUB2(wv, 4), SUB2(hv, 4), acc);
    acc = dot2(SUB2(wv, 6), SUB2(hv, 6), acc);
    return acc;
}

// Full 64-wide row dot: two independent 16-dot2 chains (ILP), summed.
#define DOTROW8(Wa, Wb, Wc, Wd, We, Wf, Wg, Wh, hp)                     \
    (d8(Wd, (hp)[3], d8(Wc, (hp)[2], d8(Wb, (hp)[1], d8(Wa, (hp)[0], 0.f)))) \
   + d8(Wh, (hp)[7], d8(Wg, (hp)[6], d8(Wf, (hp)[5], d8(We, (hp)[4], 0.f)))))

// load 16 fp32 weights -> two h8_t (load-time only)
__device__ __forceinline__ void cvt16(const float* __restrict__ src,
                                      h8_t& a, h8_t& b) {
    const float4* p = (const float4*)src;
    float4 v0 = p[0], v1 = p[1], v2 = p[2], v3 = p[3];
    a[0] = (_Float16)v0.x; a[1] = (_Float16)v0.y;
    a[2] = (_Float16)v0.z; a[3] = (_Float16)v0.w;
    a[4] = (_Float16)v1.x; a[5] = (_Float16)v1.y;
    a[6] = (_Float16)v1.z; a[7] = (_Float16)v1.w;
    b[0] = (_Float16)v2.x; b[1] = (_Float16)v2.y;
    b[2] = (_Float16)v2.z; b[3] = (_Float16)v2.w;
    b[4] = (_Float16)v3.x; b[5] = (_Float16)v3.y;
    b[6] = (_Float16)v3.z; b[7] = (_Float16)v3.w;
}

// R13: FULL-ROW LANES + IN-WAVE CELL UPDATE, ONE BARRIER/PHASE.
// Block = 768 = 12 waves: wave -> (layer = tid>>8, cell group). Lane l:
// gate = l>>4 (i,f,g,o), cell = ((tid>>6)&3)*16 + (l&15). The 4 gate rows
// of a cell share a wave -> cell update via __shfl_xor(16/32/48), no gates
// LDS array, no separate update stage, 1 barrier per phase (R12's layer
// pipeline kept: layer L computes t = p - L, h double-buffered).
// Weights: full row per lane = 16 h8 = 32 VGPR; total demand ~55 fits the
// compiler's revealed 64-VGPR allocation target (R1..R12: it spills
// anything above ~64 regardless of attributes/pins) -> first spill-free
// design. Activations: 1/lane, zero redundancy, branchless gate select.
__global__ __launch_bounds__(768)
void lstm3_wave(const float* __restrict__ x,
                const float* __restrict__ Wih0, const float* __restrict__ Whh0,
                const float* __restrict__ bih0, const float* __restrict__ bhh0,
                const float* __restrict__ Wih1, const float* __restrict__ Whh1,
                const float* __restrict__ bih1, const float* __restrict__ bhh1,
                const float* __restrict__ Wih2, const float* __restrict__ Whh2,
                const float* __restrict__ bih2, const float* __restrict__ bhh2,
                const float* __restrict__ Wout, const float* __restrict__ bout,
                float* __restrict__ out)
{
    __shared__ __align__(16) float xs[T_STEPS * 2];       // 16 KB input seq
    __shared__ __align__(16) _Float16 h0b[2][H];          // h, 2 slots, f16
    __shared__ __align__(16) _Float16 h1b[2][H];
    __shared__ __align__(16) _Float16 h2b[2][H];
    __shared__ __align__(16) float h2f[H];                // fp32 h2 (proj)

    const int tid   = threadIdx.x;
    const int b     = blockIdx.x;
    const int layer = tid >> 8;              // wave-uniform: 0,1,2
    const int l     = tid & 63;
    const int gate  = l >> 4;                // 0:i 1:f 2:g 3:o (lane-varying)
    const int cell  = ((tid >> 6) & 3) * 16 + (l & 15);
    const int r     = gate * H + cell;       // gate row 0..255

    // ---- stage x[b,:,:] (1024 float4) ----
    {
        const float4* xsrc = (const float4*)(x + (size_t)b * T_STEPS * 2);
        ((float4*)xs)[tid] = xsrc[tid];
        if (tid < 256) ((float4*)xs)[tid + 768] = xsrc[tid + 768];
    }

    // ---- this lane's full weight row(s) -> 16 h8 = 32 VGPRs ----
    const float* m1 = (layer == 0) ? (Whh0 + r * H)
                    : (layer == 1) ? (Wih1 + r * H) : (Wih2 + r * H);
    const float* m2 = (layer == 2) ? (Whh2 + r * H) : (Whh1 + r * H);
    h8_t W0, W1, W2, W3, W4, W5, W6, W7, W8, W9, Wa, Wb, Wc, Wd, We, Wf;
    cvt16(m1,      W0, W1); cvt16(m1 + 16, W2, W3);
    cvt16(m1 + 32, W4, W5); cvt16(m1 + 48, W6, W7);
    cvt16(m2,      W8, W9); cvt16(m2 + 16, Wa, Wb);
    cvt16(m2 + 32, Wc, Wd); cvt16(m2 + 48, We, Wf);
    float wx0 = 0.f, wx1 = 0.f;
    if (layer == 0) { wx0 = Wih0[r * 2]; wx1 = Wih0[r * 2 + 1]; }
    const float* bip = (layer == 0) ? bih0 : (layer == 1) ? bih1 : bih2;
    const float* bhp = (layer == 0) ? bhh0 : (layer == 1) ? bhh1 : bhh2;
    float bias = bip[r] + bhp[r];

    asm volatile("" : "+v"(W0), "+v"(W1), "+v"(W2), "+v"(W3));
    asm volatile("" : "+v"(W4), "+v"(W5), "+v"(W6), "+v"(W7));
    asm volatile("" : "+v"(W8), "+v"(W9), "+v"(Wa), "+v"(Wb));
    asm volatile("" : "+v"(Wc), "+v"(Wd), "+v"(We), "+v"(Wf));
    asm volatile("" : "+v"(wx0), "+v"(wx1), "+v"(bias));

    if (tid < H) {
        _Float16 z = (_Float16)0.f;
        h0b[0][tid] = z; h0b[1][tid] = z;
        h1b[0][tid] = z; h1b[1][tid] = z;
        h2b[0][tid] = z; h2b[1][tid] = z;
    }
    float cst = 0.f;   // this lane's copy of its cell state (4 identical/cell)
    __syncthreads();

    const bool isg = (gate == 2);

#pragma unroll 1
    for (int p = 0; p < T_STEPS + 2; ++p) {
        const int s = (p + 1) & 1;     // read slot
        const int w = p & 1;           // write slot
        const bool on = (layer == 0) ? (p < T_STEPS)
                      : (layer == 1) ? (p >= 1 && p < T_STEPS + 1)
                                     : (p >= 2);            // wave-uniform
        if (on) {
            float pa;
            if (layer == 0) {
                const h8_t* hp = (const h8_t*)h0b[s];
                float2 xt = *(const float2*)&xs[2 * p];
                pa = bias + wx0 * xt.x + wx1 * xt.y
                   + DOTROW8(W0, W1, W2, W3, W4, W5, W6, W7, hp);
            } else if (layer == 1) {
                pa = bias
                   + DOTROW8(W0, W1, W2, W3, W4, W5, W6, W7, (const h8_t*)h0b[s])
                   + DOTROW8(W8, W9, Wa, Wb, Wc, Wd, We, Wf, (const h8_t*)h1b[s]);
            } else {
                pa = bias
                   + DOTROW8(W0, W1, W2, W3, W4, W5, W6, W7, (const h8_t*)h1b[s])
                   + DOTROW8(W8, W9, Wa, Wb, Wc, Wd, We, Wf, (const h8_t*)h2b[s]);
            }
            // branchless activation: sigmoid(pa) or tanh(pa) for g-gate
            float zz  = isg ? (-2.0f * pa) : (-pa);
            float ex  = __expf(zz);
            float rr  = 1.0f / (1.0f + ex);
            float act = isg ? (2.0f * rr - 1.0f) : rr;
            // in-wave gather of the cell's 4 gate activations
            float a16 = __shfl_xor(act, 16);   // gate^1
            float a32 = __shfl_xor(act, 32);   // gate^2
            float a48 = __shfl_xor(act, 48);   // gate^3
            const bool b0 = (gate & 1), b1 = (gate & 2);
            float q0 = b0 ? a16 : act, q1 = b0 ? act : a16;
            float q2 = b0 ? a48 : a32, q3 = b0 ? a32 : a48;
            float gi = b1 ? q2 : q0;           // arr[0] = i
            float gf = b1 ? q3 : q1;           // arr[1] = f
            float gg = b1 ? q0 : q2;           // arr[2] = g
            float go = b1 ? q1 : q3;           // arr[3] = o
            cst = gf * cst + gi * gg;
            float hh = go * tanh_f(cst);
            if (l < 16) {                      // gate-0 lane writes its cell's h
                _Float16 hx = (_Float16)hh;
                if (layer == 0)      h0b[w][cell] = hx;
                else if (layer == 1) h1b[w][cell] = hx;
                else               { h2b[w][cell] = hx; h2f[cell] = hh; }
            }
        }
        __syncthreads();
    }

    // ---- fused projection: out[b,:] = h2_last @ Wout^T + bout ----
    if (tid < 11) {
        float acc = bout[tid];
#pragma unroll
        for (int jj = 0; jj < H; ++jj)
            acc += Wout[tid * H + jj] * h2f[jj];
        out[b * 11 + tid] = acc;
    }
}

extern "C" void kernel_launch(void* const* d_in, const int* in_sizes, int n_in,
                              void* d_out, int out_size, void* d_ws, size_t ws_size,
                              hipStream_t stream) {
    const float* x    = (const float*)d_in[0];
    const float* Wih0 = (const float*)d_in[1];
    const float* Whh0 = (const float*)d_in[2];
    const float* bih0 = (const float*)d_in[3];
    const float* bhh0 = (const float*)d_in[4];
    const float* Wih1 = (const float*)d_in[5];
    const float* Whh1 = (const float*)d_in[6];
    const float* bih1 = (const float*)d_in[7];
    const float* bhh1 = (const float*)d_in[8];
    const float* Wih2 = (const float*)d_in[9];
    const float* Whh2 = (const float*)d_in[10];
    const float* bih2 = (const float*)d_in[11];
    const float* bhh2 = (const float*)d_in[12];
    const float* Wout = (const float*)d_in[13];
    const float* bout = (const float*)d_in[14];
    float* out = (float*)d_out;

    lstm3_wave<<<256, 768, 0, stream>>>(x,
        Wih0, Whh0, bih0, bhh0,
        Wih1, Whh1, bih1, bhh1,
        Wih2, Whh2, bih2, bhh2,
        Wout, bout, out);
}